// Round 2
// baseline (1881.888 us; speedup 1.0000x reference)
//
#include <hip/hip_runtime.h>
#include <hip/hip_bf16.h>

typedef unsigned short u16;
typedef u16  u16x8 __attribute__((ext_vector_type(8)));
typedef u16  u16x4 __attribute__((ext_vector_type(4)));
typedef __bf16 bf16;
typedef bf16 bf16x8 __attribute__((ext_vector_type(8)));
typedef float f32x4 __attribute__((ext_vector_type(4)));

#define LDSTR 40   // LDS row stride (elements): 80B rows -> 16B aligned, 2-way-free b128 reads

__device__ __forceinline__ float b2f(u16 u){ return __uint_as_float(((unsigned)u)<<16); }
__device__ __forceinline__ u16 f2b(float f){ bf16 h = (bf16)f; return __builtin_bit_cast(u16, h); }
__device__ __forceinline__ float lrelu(float v){ return v > 0.f ? v : 0.2f*v; }

// ---------------- prep kernels ----------------

// up_w: [i=512][o=512][3][3] -> Wup_t[a][b][o][i] = up_w[i][o][2-a][2-b] (bf16), wsq_up[o][i] = sum_hw w^2
__global__ __launch_bounds__(256) void prep_w_up(const float* __restrict__ up_w,
                                                 u16* __restrict__ Wup_t, float* __restrict__ wsq_up){
  const int t = blockIdx.x*256 + threadIdx.x;          // 512*512
  const int i = t & 511, o = t >> 9;
  const float* src = up_w + ((i<<9) + o)*9;
  float sq = 0.f;
  #pragma unroll
  for (int ky=0; ky<3; ++ky)
    #pragma unroll
    for (int kx=0; kx<3; ++kx){
      float w = src[ky*3+kx];
      sq += w*w;
      Wup_t[ (((2-ky)*3 + (2-kx))<<18) + (o<<9) + i ] = f2b(w);
    }
  wsq_up[(o<<9)+i] = sq;
}

// c_w: [o=512][i=512][3][3] -> Wc_t[tap][o][i] (bf16), wsq_c[o][i]
__global__ __launch_bounds__(256) void prep_w_c(const float* __restrict__ c_w,
                                                u16* __restrict__ Wc_t, float* __restrict__ wsq_c){
  const int t = blockIdx.x*256 + threadIdx.x;
  const int i = t & 511, o = t >> 9;
  const float* src = c_w + ((o<<9) + i)*9;
  float sq = 0.f;
  #pragma unroll
  for (int tap=0; tap<9; ++tap){
    float w = src[tap];
    sq += w*w;
    Wc_t[ (tap<<18) + (o<<9) + i ] = f2b(w);
  }
  wsq_c[(o<<9)+i] = sq;
}

// s_up/s_c/s_rgb[n][j] = v[n] @ sw[:,j] + sb[j]
__global__ __launch_bounds__(256) void prep_s(const float* __restrict__ v,
    const float* __restrict__ up_sw, const float* __restrict__ up_sb,
    const float* __restrict__ c_sw,  const float* __restrict__ c_sb,
    const float* __restrict__ rgb_sw,const float* __restrict__ rgb_sb,
    float* __restrict__ s_up, float* __restrict__ s_c, float* __restrict__ s_rgb){
  const int t = blockIdx.x*256 + threadIdx.x;          // 8*512
  const int j = t & 511, n = t >> 9;
  const float* vn = v + (n<<9);
  float a=0.f, b=0.f, c=0.f;
  for (int l=0; l<512; ++l){
    float vl = vn[l];
    a += vl*up_sw[(l<<9)+j];
    b += vl*c_sw[(l<<9)+j];
    c += vl*rgb_sw[(l<<9)+j];
  }
  s_up[t] = a + up_sb[j];
  s_c[t]  = b + c_sb[j];
  s_rgb[t]= c + rgb_sb[j];
}

// sinv[n][o] = 1/sqrt(sum_i wsq[o][i]*s[n][i]^2 + 1e-8)
__global__ __launch_bounds__(256) void prep_sigma(const float* __restrict__ wsq_up, const float* __restrict__ wsq_c,
    const float* __restrict__ s_up, const float* __restrict__ s_c,
    float* __restrict__ sinv_up, float* __restrict__ sinv_c){
  const int t = blockIdx.x*256 + threadIdx.x;          // 8*512
  const int o = t & 511, n = t >> 9;
  const float* su = s_up + (n<<9);
  const float* sc = s_c  + (n<<9);
  const float* wu = wsq_up + (o<<9);
  const float* wc = wsq_c  + (o<<9);
  float au=0.f, ac=0.f;
  for (int l=0; l<512; ++l){
    float s1 = su[l]; au += wu[l]*s1*s1;
    float s2 = sc[l]; ac += wc[l]*s2*s2;
  }
  sinv_up[t] = 1.f/sqrtf(au + 1e-8f);
  sinv_c[t]  = 1.f/sqrtf(ac + 1e-8f);
}

// x [8,512,32,32] f32 -> xp bf16 padded [ch=4096][33 rows][36 cols] (border pre-zeroed by memset)
__global__ __launch_bounds__(256) void fill_xp(const float* __restrict__ x, u16* __restrict__ xp){
  const int t = blockIdx.x*256 + threadIdx.x;          // 8*512*32*8
  const int q4 = (t&7)<<2;
  const int p  = (t>>3)&31;
  const int ch = t>>8;                                  // [0,4096)
  const float4 vx = *(const float4*)&x[ (((ch<<5)+p)<<5) + q4 ];
  u16x4 o;
  o[0]=f2b(vx.x); o[1]=f2b(vx.y); o[2]=f2b(vx.z); o[3]=f2b(vx.w);
  *(u16x4*)&xp[ (ch*33 + p)*36 + q4 ] = o;
}

// ---------------- up-conv (modulated conv_transpose 2x) ----------------
// out[n,o,y,x] = sum_{i,a,b: (y+a) odd,(x+b) odd} xp[n,i,(y+a-1)/2,(x+b-1)/2] * Wup_t[a][b][o][i]*s_up[n][i]
// grid: bid = ((n*4+cls)*8+tile)*4+og ; block tile 128 o x 128 class-pixels (4 r-rows x 32 c)
__global__ __launch_bounds__(256) void up_conv_k(
    const u16* __restrict__ xp, const u16* __restrict__ Wup_t,
    const float* __restrict__ s_up, const float* __restrict__ sinv_up,
    const float* __restrict__ up_b, const float* __restrict__ noise1,
    const float* __restrict__ nstr, u16* __restrict__ h1p)
{
  __shared__ __align__(16) u16 Al[128*LDSTR];
  __shared__ __align__(16) u16 Bl[128*LDSTR];
  const int bid = blockIdx.x;
  const int og = bid & 3, tile = (bid>>2)&7, cls = (bid>>5)&3, n = bid>>7;
  const int cy = cls>>1, cx = cls&1;
  const int o0 = og<<7, r0 = tile<<2;
  const int tid = threadIdx.x;
  const int lane = tid & 63, wave = tid>>6;
  const int l15 = lane & 15, l4 = lane>>4;
  const int wm = wave>>1, wn = wave&1;
  const float* sU = s_up + (n<<9);

  f32x4 acc[4][4];
  #pragma unroll
  for (int i2=0;i2<4;++i2)
    #pragma unroll
    for (int j2=0;j2<4;++j2){ f32x4 z = {0.f,0.f,0.f,0.f}; acc[i2][j2]=z; }

  const int a0 = cy?0:1, a1 = cy?2:1, ast = cy?2:1;
  const int b0 = cx?0:1, b1 = cx?2:1, bst = cx?2:1;
  for (int a=a0; a<=a1; a+=ast){
    const int dp = (cy + a - 1)>>1;
    for (int b=b0; b<=b1; b+=bst){
      const int dq = (cx + b - 1)>>1;
      const u16* Wt = Wup_t + ((a*3+b)<<18);
      for (int ci=0; ci<16; ++ci){
        const int i0 = ci<<5;
        __syncthreads();
        { // stage A (weights * s), 128x32
          const int o = tid>>1, sg = (tid&1)<<4;
          const u16* src = Wt + (((o0+o)<<9) + i0 + sg);
          u16x8 w0 = *(const u16x8*)src;
          u16x8 w1 = *(const u16x8*)(src+8);
          u16x8 d0, d1;
          #pragma unroll
          for (int e=0;e<8;++e){
            d0[e] = f2b(b2f(w0[e]) * sU[i0+sg+e]);
            d1[e] = f2b(b2f(w1[e]) * sU[i0+sg+8+e]);
          }
          *(u16x8*)&Al[o*LDSTR + sg]     = d0;
          *(u16x8*)&Al[o*LDSTR + sg + 8] = d1;
        }
        { // stage B: xp gather, 32 ch x 128 px -> Bl[px][i]
          const int chbase = (n<<9) + i0;
          #pragma unroll
          for (int e=0;e<16;++e){
            const int idx = (e<<8) + tid;
            const int c  = idx&31, rr = (idx>>5)&3, i = idx>>7;
            const u16 val = xp[ (chbase+i)*1188 + (r0+rr+dp)*36 + (c+dq) ];
            Bl[ ((rr<<5)+c)*LDSTR + i ] = val;
          }
        }
        __syncthreads();
        bf16x8 af[4], bfr[4];
        #pragma unroll
        for (int fm=0; fm<4; ++fm)
          af[fm] = *(const bf16x8*)&Al[ ((wm<<6)+(fm<<4)+l15)*LDSTR + (l4<<3) ];
        #pragma unroll
        for (int fn=0; fn<4; ++fn)
          bfr[fn] = *(const bf16x8*)&Bl[ ((wn<<6)+(fn<<4)+l15)*LDSTR + (l4<<3) ];
        #pragma unroll
        for (int fm=0; fm<4; ++fm)
          #pragma unroll
          for (int fn=0; fn<4; ++fn)
            acc[fm][fn] = __builtin_amdgcn_mfma_f32_16x16x32_bf16(af[fm], bfr[fn], acc[fm][fn], 0,0,0);
      }
    }
  }
  // epilogue: demod + bias + noise + lrelu -> h1p (bf16, padded [66][66], interior +1)
  const float ns = nstr[0];
  const float* sv = sinv_up + (n<<9);
  #pragma unroll
  for (int fm=0; fm<4; ++fm){
    #pragma unroll
    for (int r=0;r<4;++r){
      const int oo = o0 + (wm<<6) + (fm<<4) + (l4<<2) + r;
      const float si = sv[oo], bb = up_b[oo];
      #pragma unroll
      for (int fn=0; fn<4; ++fn){
        const int px = (wn<<6) + (fn<<4) + l15;
        const int rr = px>>5, c = px&31;
        const int Y = ((r0+rr)<<1) + cy, X = (c<<1) + cx;
        float valf = acc[fm][fn][r]*si + bb + ns*noise1[(n<<12) + (Y<<6) + X];
        valf = lrelu(valf);
        h1p[ ((n<<9)+oo)*4356 + (Y+1)*66 + (X+1) ] = f2b(valf);
      }
    }
  }
}

// ---------------- 3x3 modulated conv ----------------
// grid: bid = (n*32 + yp)*4 + og ; tile 128 o x (2 rows x 64 x)
__global__ __launch_bounds__(256) void conv3x3_k(
    const u16* __restrict__ h1p, const u16* __restrict__ Wc_t,
    const float* __restrict__ s_c, const float* __restrict__ sinv_c,
    const float* __restrict__ c_b, const float* __restrict__ noise2,
    const float* __restrict__ nstr, float* __restrict__ outh)
{
  __shared__ __align__(16) u16 Al[128*LDSTR];
  __shared__ __align__(16) u16 Bl[128*LDSTR];
  const int bid = blockIdx.x;
  const int og = bid & 3, yp = (bid>>2)&31, n = bid>>7;
  const int o0 = og<<7, y0 = yp<<1;
  const int tid = threadIdx.x;
  const int lane = tid & 63, wave = tid>>6;
  const int l15 = lane & 15, l4 = lane>>4;
  const int wm = wave>>1, wn = wave&1;
  const float* sC = s_c + (n<<9);

  f32x4 acc[4][4];
  #pragma unroll
  for (int i2=0;i2<4;++i2)
    #pragma unroll
    for (int j2=0;j2<4;++j2){ f32x4 z = {0.f,0.f,0.f,0.f}; acc[i2][j2]=z; }

  for (int tap=0; tap<9; ++tap){
    const int ky = tap/3, kx = tap - ky*3;
    const u16* Wt = Wc_t + (tap<<18);
    for (int ci=0; ci<16; ++ci){
      const int i0 = ci<<5;
      __syncthreads();
      { // stage A
        const int o = tid>>1, sg = (tid&1)<<4;
        const u16* src = Wt + (((o0+o)<<9) + i0 + sg);
        u16x8 w0 = *(const u16x8*)src;
        u16x8 w1 = *(const u16x8*)(src+8);
        u16x8 d0, d1;
        #pragma unroll
        for (int e=0;e<8;++e){
          d0[e] = f2b(b2f(w0[e]) * sC[i0+sg+e]);
          d1[e] = f2b(b2f(w1[e]) * sC[i0+sg+8+e]);
        }
        *(u16x8*)&Al[o*LDSTR + sg]     = d0;
        *(u16x8*)&Al[o*LDSTR + sg + 8] = d1;
      }
      { // stage B: h1p gather, 32 ch x 128 px
        const int chbase = (n<<9) + i0;
        #pragma unroll
        for (int e=0;e<16;++e){
          const int idx = (e<<8) + tid;
          const int xq = idx&63, ry = (idx>>6)&1, i = idx>>7;
          Bl[ ((ry<<6)+xq)*LDSTR + i ] = h1p[ (chbase+i)*4356 + (y0+ry+ky)*66 + (xq+kx) ];
        }
      }
      __syncthreads();
      bf16x8 af[4], bfr[4];
      #pragma unroll
      for (int fm=0; fm<4; ++fm)
        af[fm] = *(const bf16x8*)&Al[ ((wm<<6)+(fm<<4)+l15)*LDSTR + (l4<<3) ];
      #pragma unroll
      for (int fn=0; fn<4; ++fn)
        bfr[fn] = *(const bf16x8*)&Bl[ ((wn<<6)+(fn<<4)+l15)*LDSTR + (l4<<3) ];
      #pragma unroll
      for (int fm=0; fm<4; ++fm)
        #pragma unroll
        for (int fn=0; fn<4; ++fn)
          acc[fm][fn] = __builtin_amdgcn_mfma_f32_16x16x32_bf16(af[fm], bfr[fn], acc[fm][fn], 0,0,0);
    }
  }
  const float ns = nstr[0];
  const float* sv = sinv_c + (n<<9);
  #pragma unroll
  for (int fm=0; fm<4; ++fm){
    #pragma unroll
    for (int r=0;r<4;++r){
      const int oo = o0 + (wm<<6) + (fm<<4) + (l4<<2) + r;
      const float si = sv[oo], bb = c_b[oo];
      #pragma unroll
      for (int fn=0; fn<4; ++fn){
        const int px = (wn<<6) + (fn<<4) + l15;
        const int ry = px>>6, xq = px&63;
        const int Y = y0 + ry;
        float valf = acc[fm][fn][r]*si + bb + ns*noise2[(n<<12) + (Y<<6) + xq];
        outh[ (((n<<9)+oo)<<12) + (Y<<6) + xq ] = lrelu(valf);
      }
    }
  }
}

// ---------------- toRGB + bilinear skip ----------------
// block per (n,Y): rgb[c] = lrelu(sum_o h2*s_rgb*w + b); out1 = yup + rgb
__global__ __launch_bounds__(256) void rgb_k(const float* __restrict__ h2,
    const float* __restrict__ s_rgb, const float* __restrict__ rgb_w, const float* __restrict__ rgb_b,
    const float* __restrict__ yin, float* __restrict__ out1)
{
  __shared__ float coef[3][512];
  __shared__ float part[4][3][64];
  const int n = blockIdx.x>>6, Y = blockIdx.x&63;
  const int tid = threadIdx.x;
  for (int t = tid; t < 1536; t += 256){
    int c = t>>9, o = t&511;
    coef[c][o] = rgb_w[(c<<9)+o]*s_rgb[(n<<9)+o];
  }
  __syncthreads();
  const int wave = tid>>6, lane = tid&63;
  const float* base = h2 + ((size_t)(n<<9))*4096 + (Y<<6) + lane;
  float a0=0.f,a1=0.f,a2=0.f;
  for (int e=0;e<128;++e){
    int o = (wave<<7)+e;
    float h = base[(size_t)o<<12];
    a0 += h*coef[0][o]; a1 += h*coef[1][o]; a2 += h*coef[2][o];
  }
  part[wave][0][lane]=a0; part[wave][1][lane]=a1; part[wave][2][lane]=a2;
  __syncthreads();
  if (tid < 192){
    const int c = tid>>6, x2 = tid&63;
    float s = part[0][c][x2]+part[1][c][x2]+part[2][c][x2]+part[3][c][x2] + rgb_b[c];
    s = lrelu(s);
    // bilinear upsample of y (half-pixel, edge-clamped)
    float fy = 0.5f*Y - 0.25f, fx = 0.5f*x2 - 0.25f;
    int y0i = (int)floorf(fy); float wy = fy - y0i;
    int x0i = (int)floorf(fx); float wx = fx - x0i;
    int y0c = y0i<0?0:y0i, y1c = y0i+1>31?31:y0i+1;
    int x0c = x0i<0?0:x0i, x1c = x0i+1>31?31:x0i+1;
    const float* yb = yin + ((n*3 + c)<<10);
    float v00 = yb[(y0c<<5)+x0c], v01 = yb[(y0c<<5)+x1c];
    float v10 = yb[(y1c<<5)+x0c], v11 = yb[(y1c<<5)+x1c];
    float yup = (1.f-wy)*((1.f-wx)*v00 + wx*v01) + wy*((1.f-wx)*v10 + wx*v11);
    out1[ (((n*3+c)<<12)) + (Y<<6) + x2 ] = yup + s;
  }
}

// ---------------- launch ----------------
extern "C" void kernel_launch(void* const* d_in, const int* in_sizes, int n_in,
                              void* d_out, int out_size, void* d_ws, size_t ws_size,
                              hipStream_t stream) {
  const float* x      = (const float*)d_in[0];
  const float* v      = (const float*)d_in[1];
  const float* yin    = (const float*)d_in[2];
  const float* noise1 = (const float*)d_in[3];
  const float* noise2 = (const float*)d_in[4];
  const float* up_w   = (const float*)d_in[5];
  const float* up_b   = (const float*)d_in[6];
  const float* up_sw  = (const float*)d_in[7];
  const float* up_sb  = (const float*)d_in[8];
  const float* c_w    = (const float*)d_in[9];
  const float* c_b    = (const float*)d_in[10];
  const float* c_sw   = (const float*)d_in[11];
  const float* c_sb   = (const float*)d_in[12];
  const float* rgb_w  = (const float*)d_in[13];
  const float* rgb_b  = (const float*)d_in[14];
  const float* rgb_sw = (const float*)d_in[15];
  const float* rgb_sb = (const float*)d_in[16];
  const float* nstr   = (const float*)d_in[17];

  char* w = (char*)d_ws;
  u16*   Wup_t  = (u16*)(w);                  //  4,718,592 B (512*512*9*2)
  u16*   Wc_t   = (u16*)(w + 4718592);        //  4,718,592 B
  float* wsq_up = (float*)(w + 9437184);      //  1,048,576 B
  float* wsq_c  = (float*)(w + 10485760);     //  1,048,576 B
  float* s_up   = (float*)(w + 11534336);     //     16,384 B
  float* s_c    = (float*)(w + 11550720);
  float* s_rgb  = (float*)(w + 11567104);
  float* sinv_up= (float*)(w + 11583488);
  float* sinv_c = (float*)(w + 11599872);
  u16*   xp     = (u16*)(w + 11616256);       //  9,732,096 B  (4096*33*36*2)
  u16*   h1p    = (u16*)(w + 21348352);       // 35,684,352 B  (4096*66*66*2); end 57,032,704
  float* outh = (float*)d_out;                 // [8,512,64,64]
  float* out1 = (float*)d_out + 16777216;      // [8,3,64,64]

  hipMemsetAsync(xp,  0, 9732096,  stream);
  hipMemsetAsync(h1p, 0, 35684352, stream);

  prep_w_up <<<1024, 256, 0, stream>>>(up_w, Wup_t, wsq_up);
  prep_w_c  <<<1024, 256, 0, stream>>>(c_w,  Wc_t,  wsq_c);
  prep_s    <<<16,   256, 0, stream>>>(v, up_sw, up_sb, c_sw, c_sb, rgb_sw, rgb_sb, s_up, s_c, s_rgb);
  prep_sigma<<<16,   256, 0, stream>>>(wsq_up, wsq_c, s_up, s_c, sinv_up, sinv_c);
  fill_xp   <<<4096, 256, 0, stream>>>(x, xp);
  up_conv_k <<<1024, 256, 0, stream>>>(xp, Wup_t, s_up, sinv_up, up_b, noise1, nstr, h1p);
  conv3x3_k <<<1024, 256, 0, stream>>>(h1p, Wc_t, s_c, sinv_c, c_b, noise2, nstr, outh);
  rgb_k     <<<512,  256, 0, stream>>>(outh, s_rgb, rgb_w, rgb_b, yin, out1);
}

// Round 3
// 484.916 us; speedup vs baseline: 3.8808x; 3.8808x over previous
//
#include <hip/hip_runtime.h>
#include <hip/hip_bf16.h>

typedef unsigned short u16;
typedef u16  u16x4 __attribute__((ext_vector_type(4)));
typedef __bf16 bf16;
typedef bf16 bf16x8 __attribute__((ext_vector_type(8)));
typedef float f32x4 __attribute__((ext_vector_type(4)));

__device__ __forceinline__ float b2f(u16 u){ return __uint_as_float(((unsigned)u)<<16); }
__device__ __forceinline__ u16 f2b(float f){ bf16 h = (bf16)f; return __builtin_bit_cast(u16, h); }
__device__ __forceinline__ float lrelu(float v){ return v > 0.f ? v : 0.2f*v; }

// async global->LDS, 16B per lane; lds base must be wave-uniform (HW adds lane*16)
__device__ __forceinline__ void gll16(const u16* g, u16* l){
  __builtin_amdgcn_global_load_lds(
    (const __attribute__((address_space(1))) unsigned int*)(const void*)g,
    (__attribute__((address_space(3))) unsigned int*)(void*)l, 16, 0, 0);
}
#define VMCNT0() asm volatile("s_waitcnt vmcnt(0)" ::: "memory")
#define BAR()    { asm volatile("" ::: "memory"); __builtin_amdgcn_s_barrier(); asm volatile("" ::: "memory"); }

// ---------------- prep kernels ----------------

// up_w: [i=512][o=512][3][3] -> Wup_t[a][b][o][i] (bf16 raw, flipped), wsq_up[o][i]
__global__ __launch_bounds__(256) void prep_w_up(const float* __restrict__ up_w,
                                                 u16* __restrict__ Wup_t, float* __restrict__ wsq_up){
  const int t = blockIdx.x*256 + threadIdx.x;          // 512*512
  const int i = t & 511, o = t >> 9;
  const float* src = up_w + ((i<<9) + o)*9;
  float sq = 0.f;
  #pragma unroll
  for (int ky=0; ky<3; ++ky)
    #pragma unroll
    for (int kx=0; kx<3; ++kx){
      float w = src[ky*3+kx];
      sq += w*w;
      Wup_t[ (((2-ky)*3 + (2-kx))<<18) + (o<<9) + i ] = f2b(w);
    }
  wsq_up[(o<<9)+i] = sq;
}

// c_w: [o=512][i=512][3][3] -> Wc_t[tap][o][i] (bf16 raw), wsq_c[o][i]
__global__ __launch_bounds__(256) void prep_w_c(const float* __restrict__ c_w,
                                                u16* __restrict__ Wc_t, float* __restrict__ wsq_c){
  const int t = blockIdx.x*256 + threadIdx.x;
  const int i = t & 511, o = t >> 9;
  const float* src = c_w + ((o<<9) + i)*9;
  float sq = 0.f;
  #pragma unroll
  for (int tap=0; tap<9; ++tap){
    float w = src[tap];
    sq += w*w;
    Wc_t[ (tap<<18) + (o<<9) + i ] = f2b(w);
  }
  wsq_c[(o<<9)+i] = sq;
}

__global__ __launch_bounds__(256) void prep_s(const float* __restrict__ v,
    const float* __restrict__ up_sw, const float* __restrict__ up_sb,
    const float* __restrict__ c_sw,  const float* __restrict__ c_sb,
    const float* __restrict__ rgb_sw,const float* __restrict__ rgb_sb,
    float* __restrict__ s_up, float* __restrict__ s_c, float* __restrict__ s_rgb){
  const int t = blockIdx.x*256 + threadIdx.x;          // 8*512
  const int j = t & 511, n = t >> 9;
  const float* vn = v + (n<<9);
  float a=0.f, b=0.f, c=0.f;
  for (int l=0; l<512; ++l){
    float vl = vn[l];
    a += vl*up_sw[(l<<9)+j];
    b += vl*c_sw[(l<<9)+j];
    c += vl*rgb_sw[(l<<9)+j];
  }
  s_up[t] = a + up_sb[j];
  s_c[t]  = b + c_sb[j];
  s_rgb[t]= c + rgb_sb[j];
}

__global__ __launch_bounds__(256) void prep_sigma(const float* __restrict__ wsq_up, const float* __restrict__ wsq_c,
    const float* __restrict__ s_up, const float* __restrict__ s_c,
    float* __restrict__ sinv_up, float* __restrict__ sinv_c){
  const int t = blockIdx.x*256 + threadIdx.x;          // 8*512
  const int o = t & 511, n = t >> 9;
  const float* su = s_up + (n<<9);
  const float* sc = s_c  + (n<<9);
  const float* wu = wsq_up + (o<<9);
  const float* wc = wsq_c  + (o<<9);
  float au=0.f, ac=0.f;
  for (int l=0; l<512; ++l){
    float s1 = su[l]; au += wu[l]*s1*s1;
    float s2 = sc[l]; ac += wc[l]*s2*s2;
  }
  sinv_up[t] = 1.f/sqrtf(au + 1e-8f);
  sinv_c[t]  = 1.f/sqrtf(ac + 1e-8f);
}

// x [8,512,32,32] f32 -> xp NHWC bf16 [n][33][36][512], value = x * s_up[n][ch]
__global__ __launch_bounds__(256) void fill_xp(const float* __restrict__ x,
    const float* __restrict__ s_up, u16* __restrict__ xp){
  const int t = blockIdx.x*256 + threadIdx.x;          // 1,048,576
  const int q4 = (t&7)<<2;
  const int p  = (t>>3)&31;
  const int chn= t>>8;                                  // n*512+ch
  const int n  = chn>>9, ch = chn&511;
  const float s = s_up[chn];
  const float4 vx = *(const float4*)&x[ (((chn<<5)+p)<<5) + q4 ];
  const int base = (((n*33 + p)*36) + q4)<<9;
  xp[base +        ch] = f2b(vx.x*s);
  xp[base +  512 + ch] = f2b(vx.y*s);
  xp[base + 1024 + ch] = f2b(vx.z*s);
  xp[base + 1536 + ch] = f2b(vx.w*s);
}

// ---------------- up-conv (modulated conv_transpose 2x) ----------------
// h1s[n][66][66][512] NHWC bf16, value = lrelu(conv/sigma + b + ns*noise1) * s_c[n][o]
__global__ __launch_bounds__(256, 2) void up_conv_k(
    const u16* __restrict__ xp, const u16* __restrict__ Wup_t,
    const float* __restrict__ sinv_up, const float* __restrict__ up_b,
    const float* __restrict__ s_c, const float* __restrict__ noise1,
    const float* __restrict__ nstr, u16* __restrict__ h1s)
{
  __shared__ __align__(16) u16 Bp[11520];   // patch [5][36][64]
  __shared__ __align__(16) u16 Aa[8192];    // A tile [128][64]
  const int bid = blockIdx.x;
  const int og = bid & 3, tile = (bid>>2)&7, cls = (bid>>5)&3, n = bid>>7;
  const int cy = cls>>1, cx = cls&1;
  const int o0 = og<<7, r0 = tile<<2;
  const int tid = threadIdx.x;
  const int lane = tid & 63, wave = tid>>6;
  const int l15 = lane & 15, l4 = lane>>4;
  const int wm = wave>>1, wn = wave&1;
  const int xsw = l15 & 7;
  const int wub = tid & ~63;

  int wtap[4], dpl[4], dql[4]; int nt=0;
  for (int a = cy?0:1; a <= (cy?2:1); a += (cy?2:1))
    for (int b = cx?0:1; b <= (cx?2:1); b += (cx?2:1)){
      wtap[nt] = a*3+b; dpl[nt] = (cy+a-1)>>1; dql[nt] = (cx+b-1)>>1; ++nt;
    }

  f32x4 acc[4][4];
  #pragma unroll
  for (int i2=0;i2<4;++i2)
    #pragma unroll
    for (int j2=0;j2<4;++j2){ f32x4 z = {0.f,0.f,0.f,0.f}; acc[i2][j2]=z; }

  #pragma unroll 1
  for (int ci=0; ci<8; ++ci){
    const int i0 = ci<<6;
    BAR();
    // stage patch: 1440 chunks of 16B
    #pragma unroll
    for (int k=0;k<6;++k){
      const int q = (k<<8) + tid;
      if (q < 1440){
        const int cell = q>>3, pc = q&7;
        const int rowl = cell/36, col = cell - rowl*36;
        const int cl = pc ^ (col&7);
        const u16* src = xp + (((n*33 + r0 + rowl)*36 + col)<<9) + i0 + (cl<<3);
        gll16(src, Bp + (((k<<8)+wub)<<3));
      }
    }
    #pragma unroll 1
    for (int t=0; t<nt; ++t){
      const int dp = dpl[t], dq = dql[t];
      // stage A
      #pragma unroll
      for (int k=0;k<4;++k){
        const int q = (k<<8) + tid;
        const int o = q>>3, pc = q&7;
        const int cl = pc ^ (o&7);
        const u16* src = Wup_t + (wtap[t]<<18) + ((o0+o)<<9) + i0 + (cl<<3);
        gll16(src, Aa + (((k<<8)+wub)<<3));
      }
      VMCNT0();
      BAR();
      bf16x8 af[4][2], bfr[4][2];
      #pragma unroll
      for (int fm=0; fm<4; ++fm){
        const int o_r = (wm<<6)+(fm<<4)+l15;
        #pragma unroll
        for (int kh=0; kh<2; ++kh)
          af[fm][kh] = *(const bf16x8*)&Aa[ (((o_r<<3) + (((kh<<2)+l4) ^ xsw))<<3) ];
      }
      #pragma unroll
      for (int fn=0; fn<4; ++fn){
        const int rr = (wn<<1) + (fn>>1), c = ((fn&1)<<4) + l15;
        const int row = rr + dp, col = c + dq;
        const int cell = row*36 + col, csw = col & 7;
        #pragma unroll
        for (int kh=0; kh<2; ++kh)
          bfr[fn][kh] = *(const bf16x8*)&Bp[ (((cell<<3) + (((kh<<2)+l4) ^ csw))<<3) ];
      }
      #pragma unroll
      for (int kh=0; kh<2; ++kh)
        #pragma unroll
        for (int fm=0; fm<4; ++fm)
          #pragma unroll
          for (int fn=0; fn<4; ++fn)
            acc[fm][fn] = __builtin_amdgcn_mfma_f32_16x16x32_bf16(af[fm][kh], bfr[fn][kh], acc[fm][fn], 0,0,0);
      BAR();
    }
  }
  // epilogue: demod + bias + noise + lrelu, fold s_c, store NHWC u16x4
  const float ns = nstr[0];
  #pragma unroll
  for (int fm=0; fm<4; ++fm){
    const int oo0 = o0 + (wm<<6) + (fm<<4) + (l4<<2);
    float si[4], bb[4], sc2[4];
    #pragma unroll
    for (int r=0;r<4;++r){
      si[r] = sinv_up[(n<<9)+oo0+r];
      bb[r] = up_b[oo0+r];
      sc2[r]= s_c[(n<<9)+oo0+r];
    }
    #pragma unroll
    for (int fn=0; fn<4; ++fn){
      const int rr = (wn<<1) + (fn>>1), c = ((fn&1)<<4) + l15;
      const int Y = ((r0+rr)<<1) + cy, X = (c<<1) + cx;
      const float nz = ns * noise1[(n<<12) + (Y<<6) + X];
      u16x4 pk;
      #pragma unroll
      for (int r=0;r<4;++r){
        float v2 = acc[fm][fn][r]*si[r] + bb[r] + nz;
        pk[r] = f2b(lrelu(v2) * sc2[r]);
      }
      *(u16x4*)&h1s[ (((n*66 + Y+1)*66 + (X+1))<<9) + oo0 ] = pk;
    }
  }
}

// ---------------- 3x3 modulated conv ----------------
__global__ __launch_bounds__(256, 2) void conv3x3_k(
    const u16* __restrict__ h1s, const u16* __restrict__ Wc_t,
    const float* __restrict__ sinv_c, const float* __restrict__ c_b,
    const float* __restrict__ noise2, const float* __restrict__ nstr,
    float* __restrict__ outh)
{
  __shared__ __align__(16) u16 Bp[16896];   // patch [4][66][64]
  __shared__ __align__(16) u16 Aa[8192];    // A tile [128][64]
  const int bid = blockIdx.x;
  const int og = bid & 3, yp = (bid>>2)&31, n = bid>>7;
  const int o0 = og<<7, y0 = yp<<1;
  const int tid = threadIdx.x;
  const int lane = tid & 63, wave = tid>>6;
  const int l15 = lane & 15, l4 = lane>>4;
  const int wm = wave>>1, wn = wave&1;
  const int xsw = l15 & 7;
  const int wub = tid & ~63;

  f32x4 acc[4][4];
  #pragma unroll
  for (int i2=0;i2<4;++i2)
    #pragma unroll
    for (int j2=0;j2<4;++j2){ f32x4 z = {0.f,0.f,0.f,0.f}; acc[i2][j2]=z; }

  #pragma unroll 1
  for (int ci=0; ci<8; ++ci){
    const int i0 = ci<<6;
    BAR();
    // stage patch: 2112 chunks of 16B (4 rows x 66 cols x 64ch)
    #pragma unroll
    for (int k=0;k<9;++k){
      if (k==8 && tid>=64) continue;
      const int q = (k<<8) + tid;
      const int cell = q>>3, pc = q&7;
      const int row = cell/66, col = cell - row*66;
      const int cl = pc ^ (col&7);
      const u16* src = h1s + (((n*66 + y0 + row)*66 + col)<<9) + i0 + (cl<<3);
      gll16(src, Bp + (((k<<8)+wub)<<3));
    }
    #pragma unroll 1
    for (int tap=0; tap<9; ++tap){
      const int ky = tap/3, kx = tap - ky*3;
      // stage A
      #pragma unroll
      for (int k=0;k<4;++k){
        const int q = (k<<8) + tid;
        const int o = q>>3, pc = q&7;
        const int cl = pc ^ (o&7);
        const u16* src = Wc_t + (tap<<18) + ((o0+o)<<9) + i0 + (cl<<3);
        gll16(src, Aa + (((k<<8)+wub)<<3));
      }
      VMCNT0();
      BAR();
      bf16x8 af[4][2], bfr[4][2];
      #pragma unroll
      for (int fm=0; fm<4; ++fm){
        const int o_r = (wm<<6)+(fm<<4)+l15;
        #pragma unroll
        for (int kh=0; kh<2; ++kh)
          af[fm][kh] = *(const bf16x8*)&Aa[ (((o_r<<3) + (((kh<<2)+l4) ^ xsw))<<3) ];
      }
      #pragma unroll
      for (int fn=0; fn<4; ++fn){
        const int colx = (fn<<4) + l15 + kx;
        const int cell = (wn + ky)*66 + colx, csw = colx & 7;
        #pragma unroll
        for (int kh=0; kh<2; ++kh)
          bfr[fn][kh] = *(const bf16x8*)&Bp[ (((cell<<3) + (((kh<<2)+l4) ^ csw))<<3) ];
      }
      #pragma unroll
      for (int kh=0; kh<2; ++kh)
        #pragma unroll
        for (int fm=0; fm<4; ++fm)
          #pragma unroll
          for (int fn=0; fn<4; ++fn)
            acc[fm][fn] = __builtin_amdgcn_mfma_f32_16x16x32_bf16(af[fm][kh], bfr[fn][kh], acc[fm][fn], 0,0,0);
      BAR();
    }
  }
  const float ns = nstr[0];
  #pragma unroll
  for (int fm=0; fm<4; ++fm){
    #pragma unroll
    for (int r=0;r<4;++r){
      const int oo = o0 + (wm<<6)+(fm<<4)+(l4<<2)+r;
      const float si = sinv_c[(n<<9)+oo], bb = c_b[oo];
      #pragma unroll
      for (int fn=0; fn<4; ++fn){
        const int xq = (fn<<4)+l15;
        const int Y = y0 + wn;
        float v2 = acc[fm][fn][r]*si + bb + ns*noise2[(n<<12)+(Y<<6)+xq];
        outh[ (((n<<9)+oo)<<12) + (Y<<6) + xq ] = lrelu(v2);
      }
    }
  }
}

// ---------------- toRGB + bilinear skip ----------------
__global__ __launch_bounds__(256) void rgb_k(const float* __restrict__ h2,
    const float* __restrict__ s_rgb, const float* __restrict__ rgb_w, const float* __restrict__ rgb_b,
    const float* __restrict__ yin, float* __restrict__ out1)
{
  __shared__ float coef[3][512];
  __shared__ float part[4][3][64];
  const int n = blockIdx.x>>6, Y = blockIdx.x&63;
  const int tid = threadIdx.x;
  for (int t = tid; t < 1536; t += 256){
    int c = t>>9, o = t&511;
    coef[c][o] = rgb_w[(c<<9)+o]*s_rgb[(n<<9)+o];
  }
  __syncthreads();
  const int wave = tid>>6, lane = tid&63;
  const float* base = h2 + ((size_t)(n<<9))*4096 + (Y<<6) + lane;
  float a0=0.f,a1=0.f,a2=0.f;
  for (int e=0;e<128;++e){
    int o = (wave<<7)+e;
    float h = base[(size_t)o<<12];
    a0 += h*coef[0][o]; a1 += h*coef[1][o]; a2 += h*coef[2][o];
  }
  part[wave][0][lane]=a0; part[wave][1][lane]=a1; part[wave][2][lane]=a2;
  __syncthreads();
  if (tid < 192){
    const int c = tid>>6, x2 = tid&63;
    float s = part[0][c][x2]+part[1][c][x2]+part[2][c][x2]+part[3][c][x2] + rgb_b[c];
    s = lrelu(s);
    float fy = 0.5f*Y - 0.25f, fx = 0.5f*x2 - 0.25f;
    int y0i = (int)floorf(fy); float wy = fy - y0i;
    int x0i = (int)floorf(fx); float wx = fx - x0i;
    int y0c = y0i<0?0:y0i, y1c = y0i+1>31?31:y0i+1;
    int x0c = x0i<0?0:x0i, x1c = x0i+1>31?31:x0i+1;
    const float* yb = yin + ((n*3 + c)<<10);
    float v00 = yb[(y0c<<5)+x0c], v01 = yb[(y0c<<5)+x1c];
    float v10 = yb[(y1c<<5)+x0c], v11 = yb[(y1c<<5)+x1c];
    float yup = (1.f-wy)*((1.f-wx)*v00 + wx*v01) + wy*((1.f-wx)*v10 + wx*v11);
    out1[ (((n*3+c)<<12)) + (Y<<6) + x2 ] = yup + s;
  }
}

// ---------------- launch ----------------
extern "C" void kernel_launch(void* const* d_in, const int* in_sizes, int n_in,
                              void* d_out, int out_size, void* d_ws, size_t ws_size,
                              hipStream_t stream) {
  const float* x      = (const float*)d_in[0];
  const float* v      = (const float*)d_in[1];
  const float* yin    = (const float*)d_in[2];
  const float* noise1 = (const float*)d_in[3];
  const float* noise2 = (const float*)d_in[4];
  const float* up_w   = (const float*)d_in[5];
  const float* up_b   = (const float*)d_in[6];
  const float* up_sw  = (const float*)d_in[7];
  const float* up_sb  = (const float*)d_in[8];
  const float* c_w    = (const float*)d_in[9];
  const float* c_b    = (const float*)d_in[10];
  const float* c_sw   = (const float*)d_in[11];
  const float* c_sb   = (const float*)d_in[12];
  const float* rgb_w  = (const float*)d_in[13];
  const float* rgb_b  = (const float*)d_in[14];
  const float* rgb_sw = (const float*)d_in[15];
  const float* rgb_sb = (const float*)d_in[16];
  const float* nstr   = (const float*)d_in[17];

  char* w = (char*)d_ws;
  u16*   Wup_t  = (u16*)(w);                  //  4,718,592 B
  u16*   Wc_t   = (u16*)(w + 4718592);        //  4,718,592 B
  float* wsq_up = (float*)(w + 9437184);      //  1,048,576 B
  float* wsq_c  = (float*)(w + 10485760);     //  1,048,576 B
  float* s_up   = (float*)(w + 11534336);
  float* s_c    = (float*)(w + 11550720);
  float* s_rgb  = (float*)(w + 11567104);
  float* sinv_up= (float*)(w + 11583488);
  float* sinv_c = (float*)(w + 11599872);
  u16*   xp     = (u16*)(w + 11616256);       //  9,732,096 B  NHWC [8][33][36][512]
  u16*   h1s    = (u16*)(w + 21348352);       // 35,684,352 B  NHWC [8][66][66][512]

  float* outh = (float*)d_out;                 // [8,512,64,64]
  float* out1 = (float*)d_out + 16777216;      // [8,3,64,64]

  hipMemsetAsync(xp,  0, 9732096,  stream);
  hipMemsetAsync(h1s, 0, 35684352, stream);

  prep_w_up <<<1024, 256, 0, stream>>>(up_w, Wup_t, wsq_up);
  prep_w_c  <<<1024, 256, 0, stream>>>(c_w,  Wc_t,  wsq_c);
  prep_s    <<<16,   256, 0, stream>>>(v, up_sw, up_sb, c_sw, c_sb, rgb_sw, rgb_sb, s_up, s_c, s_rgb);
  prep_sigma<<<16,   256, 0, stream>>>(wsq_up, wsq_c, s_up, s_c, sinv_up, sinv_c);
  fill_xp   <<<4096, 256, 0, stream>>>(x, s_up, xp);
  up_conv_k <<<1024, 256, 0, stream>>>(xp, Wup_t, sinv_up, up_b, s_c, noise1, nstr, h1s);
  conv3x3_k <<<1024, 256, 0, stream>>>(h1s, Wc_t, sinv_c, c_b, noise2, nstr, outh);
  rgb_k     <<<512,  256, 0, stream>>>(outh, s_rgb, rgb_w, rgb_b, yin, out1);
}

// Round 4
// 436.332 us; speedup vs baseline: 4.3130x; 1.1113x over previous
//
#include <hip/hip_runtime.h>
#include <hip/hip_bf16.h>

typedef unsigned short u16;
typedef u16  u16x4 __attribute__((ext_vector_type(4)));
typedef u16  u16x8 __attribute__((ext_vector_type(8)));
typedef __bf16 bf16;
typedef bf16 bf16x8 __attribute__((ext_vector_type(8)));
typedef float f32x4 __attribute__((ext_vector_type(4)));

__device__ __forceinline__ float b2f(u16 u){ return __uint_as_float(((unsigned)u)<<16); }
__device__ __forceinline__ u16 f2b(float f){ bf16 h = (bf16)f; return __builtin_bit_cast(u16, h); }
__device__ __forceinline__ float lrelu(float v){ return v > 0.f ? v : 0.2f*v; }

// async global->LDS, 16B per lane; lds base must be wave-uniform (HW adds lane*16)
__device__ __forceinline__ void gll16(const u16* g, u16* l){
  __builtin_amdgcn_global_load_lds(
    (const __attribute__((address_space(1))) unsigned int*)(const void*)g,
    (__attribute__((address_space(3))) unsigned int*)(void*)l, 16, 0, 0);
}
#define VMCNT0() asm volatile("s_waitcnt vmcnt(0)" ::: "memory")
#define VMCNT4() asm volatile("s_waitcnt vmcnt(4)" ::: "memory")
#define BAR()    { asm volatile("" ::: "memory"); __builtin_amdgcn_s_barrier(); asm volatile("" ::: "memory"); }

// ---------------- prep kernels ----------------

// up_w: [i=512][o=512][3][3] -> Wup_t[a][b][o][i] (bf16 raw, flipped), wsq_up[o][i]
__global__ __launch_bounds__(256) void prep_w_up(const float* __restrict__ up_w,
                                                 u16* __restrict__ Wup_t, float* __restrict__ wsq_up){
  const int t = blockIdx.x*256 + threadIdx.x;          // 512*512
  const int i = t & 511, o = t >> 9;
  const float* src = up_w + ((i<<9) + o)*9;
  float sq = 0.f;
  #pragma unroll
  for (int ky=0; ky<3; ++ky)
    #pragma unroll
    for (int kx=0; kx<3; ++kx){
      float w = src[ky*3+kx];
      sq += w*w;
      Wup_t[ (((2-ky)*3 + (2-kx))<<18) + (o<<9) + i ] = f2b(w);
    }
  wsq_up[(o<<9)+i] = sq;
}

// c_w: [o=512][i=512][3][3] -> Wc_t[tap][o][i] (bf16 raw), wsq_c[o][i]
__global__ __launch_bounds__(256) void prep_w_c(const float* __restrict__ c_w,
                                                u16* __restrict__ Wc_t, float* __restrict__ wsq_c){
  const int t = blockIdx.x*256 + threadIdx.x;
  const int i = t & 511, o = t >> 9;
  const float* src = c_w + ((o<<9) + i)*9;
  float sq = 0.f;
  #pragma unroll
  for (int tap=0; tap<9; ++tap){
    float w = src[tap];
    sq += w*w;
    Wc_t[ (tap<<18) + (o<<9) + i ] = f2b(w);
  }
  wsq_c[(o<<9)+i] = sq;
}

__global__ __launch_bounds__(256) void prep_s(const float* __restrict__ v,
    const float* __restrict__ up_sw, const float* __restrict__ up_sb,
    const float* __restrict__ c_sw,  const float* __restrict__ c_sb,
    const float* __restrict__ rgb_sw,const float* __restrict__ rgb_sb,
    float* __restrict__ s_up, float* __restrict__ s_c, float* __restrict__ s_rgb){
  const int t = blockIdx.x*256 + threadIdx.x;          // 8*512
  const int j = t & 511, n = t >> 9;
  const float* vn = v + (n<<9);
  float a=0.f, b=0.f, c=0.f;
  for (int l=0; l<512; ++l){
    float vl = vn[l];
    a += vl*up_sw[(l<<9)+j];
    b += vl*c_sw[(l<<9)+j];
    c += vl*rgb_sw[(l<<9)+j];
  }
  s_up[t] = a + up_sb[j];
  s_c[t]  = b + c_sb[j];
  s_rgb[t]= c + rgb_sb[j];
}

__global__ __launch_bounds__(256) void prep_sigma(const float* __restrict__ wsq_up, const float* __restrict__ wsq_c,
    const float* __restrict__ s_up, const float* __restrict__ s_c,
    float* __restrict__ sinv_up, float* __restrict__ sinv_c){
  const int t = blockIdx.x*256 + threadIdx.x;          // 8*512
  const int o = t & 511, n = t >> 9;
  const float* su = s_up + (n<<9);
  const float* sc = s_c  + (n<<9);
  const float* wu = wsq_up + (o<<9);
  const float* wc = wsq_c  + (o<<9);
  float au=0.f, ac=0.f;
  for (int l=0; l<512; ++l){
    float s1 = su[l]; au += wu[l]*s1*s1;
    float s2 = sc[l]; ac += wc[l]*s2*s2;
  }
  sinv_up[t] = 1.f/sqrtf(au + 1e-8f);
  sinv_c[t]  = 1.f/sqrtf(ac + 1e-8f);
}

// x [8,512,32,32] f32 -> xp NHWC bf16 [n][33][36][512], value = x * s_up[n][ch]
// 256 blocks = (n,p); coalesced reads (lane=q), u16x8 writes
__global__ __launch_bounds__(256) void fill_xp(const float* __restrict__ x,
    const float* __restrict__ s_up, u16* __restrict__ xp){
  const int b = blockIdx.x;            // 256
  const int n = b>>5, p = b&31;
  const int t = threadIdx.x;
  const int q = t&31, g = t>>5;        // g 0..7
  const int cb = g<<6;
  #pragma unroll
  for (int j=0;j<8;++j){
    const int ch0 = cb + (j<<3);
    u16x8 pk;
    #pragma unroll
    for (int e=0;e<8;++e){
      float vv = x[ (((n<<9)+ch0+e)<<10) + (p<<5) + q ] * s_up[(n<<9)+ch0+e];
      pk[e] = f2b(vv);
    }
    *(u16x8*)&xp[ (((n*33+p)*36 + q)<<9) + ch0 ] = pk;
  }
}

// ---------------- up-conv (modulated conv_transpose 2x) ----------------
// h1s[n][66][66][512] NHWC bf16, value = lrelu(conv/sigma + b + ns*noise1) * s_c[n][o]
__global__ __launch_bounds__(256, 2) void up_conv_k(
    const u16* __restrict__ xp, const u16* __restrict__ Wup_t,
    const float* __restrict__ sinv_up, const float* __restrict__ up_b,
    const float* __restrict__ s_c, const float* __restrict__ noise1,
    const float* __restrict__ nstr, u16* __restrict__ h1s)
{
  __shared__ __align__(16) u16 Bp[11520];      // patch [5][36][64]
  __shared__ __align__(16) u16 Aa[2][8192];    // A dbuf [128][64]
  const int braw = blockIdx.x;
  const int bid = ((braw&7)<<7) | (braw>>3);   // XCD swizzle: n pinned per XCD
  const int og = bid & 3, tile = (bid>>2)&7, cls = (bid>>5)&3, n = bid>>7;
  const int cy = cls>>1, cx = cls&1;
  const int o0 = og<<7, r0 = tile<<2;
  const int tid = threadIdx.x;
  const int lane = tid & 63, wave = tid>>6;
  const int l15 = lane & 15, l4 = lane>>4;
  const int wm = wave>>1, wn = wave&1;
  const int xsw = l15 & 7;
  const int wub = tid & ~63;

  int wtap[4], dpl[4], dql[4]; int nt=0;
  for (int a = cy?0:1; a <= (cy?2:1); a += (cy?2:1))
    for (int b = cx?0:1; b <= (cx?2:1); b += (cx?2:1)){
      wtap[nt] = a*3+b; dpl[nt] = (cy+a-1)>>1; dql[nt] = (cx+b-1)>>1; ++nt;
    }

  f32x4 acc[4][4];
  #pragma unroll
  for (int i2=0;i2<4;++i2)
    #pragma unroll
    for (int j2=0;j2<4;++j2){ f32x4 z = {0.f,0.f,0.f,0.f}; acc[i2][j2]=z; }

  #pragma unroll 1
  for (int ci=0; ci<8; ++ci){
    const int i0 = ci<<6;
    // boundary stage: patch(ci) + A(tap0) -> buf0 ; prior reads fenced by last end-BAR
    #pragma unroll
    for (int k=0;k<6;++k){
      const int q = (k<<8) + tid;
      if (q < 1440){
        const int cell = q>>3, pc = q&7;
        const int rowl = cell/36, col = cell - rowl*36;
        const int cl = pc ^ (col&7);
        gll16(xp + (((n*33 + r0 + rowl)*36 + col)<<9) + i0 + (cl<<3),
              Bp + (((k<<8)+wub)<<3));
      }
    }
    #pragma unroll
    for (int k=0;k<4;++k){
      const int q = (k<<8) + tid;
      const int o = q>>3, pc = q&7;
      const int cl = pc ^ (o&7);
      gll16(Wup_t + (wtap[0]<<18) + ((o0+o)<<9) + i0 + (cl<<3),
            &Aa[0][ (((k<<8)+wub)<<3) ]);
    }
    VMCNT0();
    BAR();
    #pragma unroll 1
    for (int t=0; t<nt; ++t){
      const int dp = dpl[t], dq = dql[t];
      const int cur = t & 1;
      if (t+1 < nt){
        const int nxt = (t+1)&1;
        #pragma unroll
        for (int k=0;k<4;++k){
          const int q = (k<<8) + tid;
          const int o = q>>3, pc = q&7;
          const int cl = pc ^ (o&7);
          gll16(Wup_t + (wtap[t+1]<<18) + ((o0+o)<<9) + i0 + (cl<<3),
                &Aa[nxt][ (((k<<8)+wub)<<3) ]);
        }
        VMCNT4();
      } else {
        VMCNT0();
      }
      BAR();
      bf16x8 af[4][2], bfr[4][2];
      #pragma unroll
      for (int fm=0; fm<4; ++fm){
        const int o_r = (wm<<6)+(fm<<4)+l15;
        #pragma unroll
        for (int kh=0; kh<2; ++kh)
          af[fm][kh] = *(const bf16x8*)&Aa[cur][ (((o_r<<3) + (((kh<<2)+l4) ^ xsw))<<3) ];
      }
      #pragma unroll
      for (int fn=0; fn<4; ++fn){
        const int rr = (wn<<1) + (fn>>1), c = ((fn&1)<<4) + l15;
        const int row = rr + dp, col = c + dq;
        const int cell = row*36 + col, csw = col & 7;
        #pragma unroll
        for (int kh=0; kh<2; ++kh)
          bfr[fn][kh] = *(const bf16x8*)&Bp[ (((cell<<3) + (((kh<<2)+l4) ^ csw))<<3) ];
      }
      __builtin_amdgcn_s_setprio(1);
      #pragma unroll
      for (int kh=0; kh<2; ++kh)
        #pragma unroll
        for (int fm=0; fm<4; ++fm)
          #pragma unroll
          for (int fn=0; fn<4; ++fn)
            acc[fm][fn] = __builtin_amdgcn_mfma_f32_16x16x32_bf16(af[fm][kh], bfr[fn][kh], acc[fm][fn], 0,0,0);
      __builtin_amdgcn_s_setprio(0);
      BAR();
    }
  }
  // epilogue: demod + bias + noise + lrelu, fold s_c, store NHWC u16x4
  const float ns = nstr[0];
  #pragma unroll
  for (int fm=0; fm<4; ++fm){
    const int oo0 = o0 + (wm<<6) + (fm<<4) + (l4<<2);
    float si[4], bb[4], sc2[4];
    #pragma unroll
    for (int r=0;r<4;++r){
      si[r] = sinv_up[(n<<9)+oo0+r];
      bb[r] = up_b[oo0+r];
      sc2[r]= s_c[(n<<9)+oo0+r];
    }
    #pragma unroll
    for (int fn=0; fn<4; ++fn){
      const int rr = (wn<<1) + (fn>>1), c = ((fn&1)<<4) + l15;
      const int Y = ((r0+rr)<<1) + cy, X = (c<<1) + cx;
      const float nz = ns * noise1[(n<<12) + (Y<<6) + X];
      u16x4 pk;
      #pragma unroll
      for (int r=0;r<4;++r){
        float v2 = acc[fm][fn][r]*si[r] + bb[r] + nz;
        pk[r] = f2b(lrelu(v2) * sc2[r]);
      }
      *(u16x4*)&h1s[ (((n*66 + Y+1)*66 + (X+1))<<9) + oo0 ] = pk;
    }
  }
}

// ---------------- 3x3 modulated conv ----------------
__global__ __launch_bounds__(256, 2) void conv3x3_k(
    const u16* __restrict__ h1s, const u16* __restrict__ Wc_t,
    const float* __restrict__ sinv_c, const float* __restrict__ c_b,
    const float* __restrict__ noise2, const float* __restrict__ nstr,
    float* __restrict__ outh)
{
  __shared__ __align__(16) u16 Bp[16896];      // patch [4][66][64]
  __shared__ __align__(16) u16 Aa[2][8192];    // A dbuf [128][64]
  const int braw = blockIdx.x;
  const int bid = ((braw&7)<<7) | (braw>>3);   // XCD swizzle
  const int og = bid & 3, yp = (bid>>2)&31, n = bid>>7;
  const int o0 = og<<7, y0 = yp<<1;
  const int tid = threadIdx.x;
  const int lane = tid & 63, wave = tid>>6;
  const int l15 = lane & 15, l4 = lane>>4;
  const int wm = wave>>1, wn = wave&1;
  const int xsw = l15 & 7;
  const int wub = tid & ~63;

  f32x4 acc[4][4];
  #pragma unroll
  for (int i2=0;i2<4;++i2)
    #pragma unroll
    for (int j2=0;j2<4;++j2){ f32x4 z = {0.f,0.f,0.f,0.f}; acc[i2][j2]=z; }

  #pragma unroll 1
  for (int ci=0; ci<8; ++ci){
    const int i0 = ci<<6;
    // boundary stage: patch(ci) + A(tap0) -> buf0
    #pragma unroll
    for (int k=0;k<9;++k){
      if (k==8 && tid>=64) continue;
      const int q = (k<<8) + tid;
      const int cell = q>>3, pc = q&7;
      const int row = cell/66, col = cell - row*66;
      const int cl = pc ^ (col&7);
      gll16(h1s + (((n*66 + y0 + row)*66 + col)<<9) + i0 + (cl<<3),
            Bp + (((k<<8)+wub)<<3));
    }
    #pragma unroll
    for (int k=0;k<4;++k){
      const int q = (k<<8) + tid;
      const int o = q>>3, pc = q&7;
      const int cl = pc ^ (o&7);
      gll16(Wc_t + ((o0+o)<<9) + i0 + (cl<<3),
            &Aa[0][ (((k<<8)+wub)<<3) ]);
    }
    VMCNT0();
    BAR();
    #pragma unroll 1
    for (int tap=0; tap<9; ++tap){
      const int ky = tap/3, kx = tap - ky*3;
      const int cur = tap & 1;
      if (tap < 8){
        const int nxt = (tap+1)&1;
        #pragma unroll
        for (int k=0;k<4;++k){
          const int q = (k<<8) + tid;
          const int o = q>>3, pc = q&7;
          const int cl = pc ^ (o&7);
          gll16(Wc_t + ((tap+1)<<18) + ((o0+o)<<9) + i0 + (cl<<3),
                &Aa[nxt][ (((k<<8)+wub)<<3) ]);
        }
        VMCNT4();
      } else {
        VMCNT0();
      }
      BAR();
      bf16x8 af[4][2], bfr[4][2];
      #pragma unroll
      for (int fm=0; fm<4; ++fm){
        const int o_r = (wm<<6)+(fm<<4)+l15;
        #pragma unroll
        for (int kh=0; kh<2; ++kh)
          af[fm][kh] = *(const bf16x8*)&Aa[cur][ (((o_r<<3) + (((kh<<2)+l4) ^ xsw))<<3) ];
      }
      #pragma unroll
      for (int fn=0; fn<4; ++fn){
        const int colx = (fn<<4) + l15 + kx;
        const int cell = (wn + ky)*66 + colx, csw = colx & 7;
        #pragma unroll
        for (int kh=0; kh<2; ++kh)
          bfr[fn][kh] = *(const bf16x8*)&Bp[ (((cell<<3) + (((kh<<2)+l4) ^ csw))<<3) ];
      }
      __builtin_amdgcn_s_setprio(1);
      #pragma unroll
      for (int kh=0; kh<2; ++kh)
        #pragma unroll
        for (int fm=0; fm<4; ++fm)
          #pragma unroll
          for (int fn=0; fn<4; ++fn)
            acc[fm][fn] = __builtin_amdgcn_mfma_f32_16x16x32_bf16(af[fm][kh], bfr[fn][kh], acc[fm][fn], 0,0,0);
      __builtin_amdgcn_s_setprio(0);
      BAR();
    }
  }
  const float ns = nstr[0];
  #pragma unroll
  for (int fm=0; fm<4; ++fm){
    #pragma unroll
    for (int r=0;r<4;++r){
      const int oo = o0 + (wm<<6)+(fm<<4)+(l4<<2)+r;
      const float si = sinv_c[(n<<9)+oo], bb = c_b[oo];
      #pragma unroll
      for (int fn=0; fn<4; ++fn){
        const int xq = (fn<<4)+l15;
        const int Y = y0 + wn;
        float v2 = acc[fm][fn][r]*si + bb + ns*noise2[(n<<12)+(Y<<6)+xq];
        outh[ (((n<<9)+oo)<<12) + (Y<<6) + xq ] = lrelu(v2);
      }
    }
  }
}

// ---------------- toRGB + bilinear skip ----------------
__global__ __launch_bounds__(256) void rgb_k(const float* __restrict__ h2,
    const float* __restrict__ s_rgb, const float* __restrict__ rgb_w, const float* __restrict__ rgb_b,
    const float* __restrict__ yin, float* __restrict__ out1)
{
  __shared__ float coef[3][512];
  __shared__ float part[4][3][64];
  const int braw = blockIdx.x;
  const int sb = ((braw&7)<<6) | (braw>>3);    // XCD swizzle (512 blocks)
  const int n = sb>>6, Y = sb&63;
  const int tid = threadIdx.x;
  for (int t = tid; t < 1536; t += 256){
    int c = t>>9, o = t&511;
    coef[c][o] = rgb_w[(c<<9)+o]*s_rgb[(n<<9)+o];
  }
  __syncthreads();
  const int wave = tid>>6, lane = tid&63;
  const float* base = h2 + ((size_t)(n<<9))*4096 + (Y<<6) + lane;
  float a0=0.f,a1=0.f,a2=0.f;
  for (int e=0;e<128;++e){
    int o = (wave<<7)+e;
    float h = base[(size_t)o<<12];
    a0 += h*coef[0][o]; a1 += h*coef[1][o]; a2 += h*coef[2][o];
  }
  part[wave][0][lane]=a0; part[wave][1][lane]=a1; part[wave][2][lane]=a2;
  __syncthreads();
  if (tid < 192){
    const int c = tid>>6, x2 = tid&63;
    float s = part[0][c][x2]+part[1][c][x2]+part[2][c][x2]+part[3][c][x2] + rgb_b[c];
    s = lrelu(s);
    float fy = 0.5f*Y - 0.25f, fx = 0.5f*x2 - 0.25f;
    int y0i = (int)floorf(fy); float wy = fy - y0i;
    int x0i = (int)floorf(fx); float wx = fx - x0i;
    int y0c = y0i<0?0:y0i, y1c = y0i+1>31?31:y0i+1;
    int x0c = x0i<0?0:x0i, x1c = x0i+1>31?31:x0i+1;
    const float* yb = yin + ((n*3 + c)<<10);
    float v00 = yb[(y0c<<5)+x0c], v01 = yb[(y0c<<5)+x1c];
    float v10 = yb[(y1c<<5)+x0c], v11 = yb[(y1c<<5)+x1c];
    float yup = (1.f-wy)*((1.f-wx)*v00 + wx*v01) + wy*((1.f-wx)*v10 + wx*v11);
    out1[ (((n*3+c)<<12)) + (Y<<6) + x2 ] = yup + s;
  }
}

// ---------------- launch ----------------
extern "C" void kernel_launch(void* const* d_in, const int* in_sizes, int n_in,
                              void* d_out, int out_size, void* d_ws, size_t ws_size,
                              hipStream_t stream) {
  const float* x      = (const float*)d_in[0];
  const float* v      = (const float*)d_in[1];
  const float* yin    = (const float*)d_in[2];
  const float* noise1 = (const float*)d_in[3];
  const float* noise2 = (const float*)d_in[4];
  const float* up_w   = (const float*)d_in[5];
  const float* up_b   = (const float*)d_in[6];
  const float* up_sw  = (const float*)d_in[7];
  const float* up_sb  = (const float*)d_in[8];
  const float* c_w    = (const float*)d_in[9];
  const float* c_b    = (const float*)d_in[10];
  const float* c_sw   = (const float*)d_in[11];
  const float* c_sb   = (const float*)d_in[12];
  const float* rgb_w  = (const float*)d_in[13];
  const float* rgb_b  = (const float*)d_in[14];
  const float* rgb_sw = (const float*)d_in[15];
  const float* rgb_sb = (const float*)d_in[16];
  const float* nstr   = (const float*)d_in[17];

  char* w = (char*)d_ws;
  u16*   Wup_t  = (u16*)(w);                  //  4,718,592 B
  u16*   Wc_t   = (u16*)(w + 4718592);        //  4,718,592 B
  float* wsq_up = (float*)(w + 9437184);      //  1,048,576 B
  float* wsq_c  = (float*)(w + 10485760);     //  1,048,576 B
  float* s_up   = (float*)(w + 11534336);
  float* s_c    = (float*)(w + 11550720);
  float* s_rgb  = (float*)(w + 11567104);
  float* sinv_up= (float*)(w + 11583488);
  float* sinv_c = (float*)(w + 11599872);
  u16*   xp     = (u16*)(w + 11616256);       //  9,732,096 B  NHWC [8][33][36][512]
  u16*   h1s    = (u16*)(w + 21348352);       // 35,684,352 B  NHWC [8][66][66][512]

  float* outh = (float*)d_out;                 // [8,512,64,64]
  float* out1 = (float*)d_out + 16777216;      // [8,3,64,64]

  hipMemsetAsync(xp,  0, 9732096,  stream);
  hipMemsetAsync(h1s, 0, 35684352, stream);

  prep_w_up <<<1024, 256, 0, stream>>>(up_w, Wup_t, wsq_up);
  prep_w_c  <<<1024, 256, 0, stream>>>(c_w,  Wc_t,  wsq_c);
  prep_s    <<<16,   256, 0, stream>>>(v, up_sw, up_sb, c_sw, c_sb, rgb_sw, rgb_sb, s_up, s_c, s_rgb);
  prep_sigma<<<16,   256, 0, stream>>>(wsq_up, wsq_c, s_up, s_c, sinv_up, sinv_c);
  fill_xp   <<<256,  256, 0, stream>>>(x, s_up, xp);
  up_conv_k <<<1024, 256, 0, stream>>>(xp, Wup_t, sinv_up, up_b, s_c, noise1, nstr, h1s);
  conv3x3_k <<<1024, 256, 0, stream>>>(h1s, Wc_t, sinv_c, c_b, noise2, nstr, outh);
  rgb_k     <<<512,  256, 0, stream>>>(outh, s_rgb, rgb_w, rgb_b, yin, out1);
}